// Round 17
// baseline (103.969 us; speedup 1.0000x reference)
//
#include <hip/hip_runtime.h>
#include <hip/hip_bf16.h>
#include <math.h>

#define SIM_THR 0.8f
// sqrt(2 * log2(e)): folds the /T=0.5 and the exp->exp2 conversion into the data
#define LAT_SCALE 1.6986436f
#define LN2 0.6931471805599453f
#define TILES 8   // j-tiles of 64 cols per block chunk

typedef __attribute__((ext_vector_type(8))) short short8v;   // 8 bf16
typedef __attribute__((ext_vector_type(4))) float f32x4;
typedef __attribute__((ext_vector_type(4))) _Float16 half4v; // 4 f16

__device__ __forceinline__ void glds16(const void* g, void* l) {
    __builtin_amdgcn_global_load_lds(
        (const __attribute__((address_space(1))) void*)g,
        (__attribute__((address_space(3))) void*)l, 16, 0, 0);
}

__device__ __forceinline__ float fexp2(float x) {
#if __has_builtin(__builtin_amdgcn_exp2f)
    return __builtin_amdgcn_exp2f(x);
#else
    return exp2f(x);
#endif
}

// ---------------- fused normalize: lat rows -> bf16 (scaled) + abr rows -> f16 ----------------
__global__ __launch_bounds__(256) void k_norm(const float* __restrict__ lat,
                                              const float* __restrict__ abr,
                                              __hip_bfloat16* __restrict__ lout,
                                              _Float16* __restrict__ aout, int B) {
    int nb_lat = B / 4;  // 2048
    if ((int)blockIdx.x < nb_lat) {
        int row = blockIdx.x * 4 + (threadIdx.x >> 6);
        int lane = threadIdx.x & 63;
        float2 v = reinterpret_cast<const float2*>(lat + (size_t)row * 128)[lane];
        float ss = v.x * v.x + v.y * v.y;
#pragma unroll
        for (int m = 1; m < 64; m <<= 1) ss += __shfl_xor(ss, m);
        float sc = LAT_SCALE / fmaxf(sqrtf(ss), 1e-12f);
        __hip_bfloat162 o;
        o.x = __float2bfloat16(v.x * sc);
        o.y = __float2bfloat16(v.y * sc);
        reinterpret_cast<__hip_bfloat162*>(lout + (size_t)row * 128)[lane] = o;
    } else {
        int row = (blockIdx.x - nb_lat) * 256 + threadIdx.x;
        if (row >= B) return;
        float v[6];
        float ss = 0.f;
#pragma unroll
        for (int d = 0; d < 6; ++d) { v[d] = abr[(size_t)row * 6 + d]; ss += v[d] * v[d]; }
        float sc = 1.0f / fmaxf(sqrtf(ss), 1e-12f);
#pragma unroll
        for (int d = 0; d < 6; ++d) aout[(size_t)row * 16 + d] = (_Float16)(v[d] * sc);
#pragma unroll
        for (int d = 6; d < 16; ++d) aout[(size_t)row * 16 + d] = (_Float16)0.f;
    }
}

// ---------------- triangular fused sweep (R14 skeleton + tile-skip + mirror) ----------------
// Grid (bi=x in [0,64), jc=y in [0,16)): rows [bi*128,+128) x cols [jc*512,+512) (8 tiles
// of 64). Active iff bi <= 4*jc+3; tiles jt < 2*bi skipped (t0); tiles jt>>1 == bi gated
// strictly col > row. Row stats -> rowslab[jc][row]; mirror col stats accumulated in
// per-wave LDS slots (zero-init; skipped tiles contribute 0) -> colslab[bi][col].
// sumd/sumsim cover each unordered pair once; doubled in k_final (MFMA dot is
// operand-order bitwise invariant -> exact). XCD = bi%8 (balanced 72/64 active blocks).
__global__ __launch_bounds__(256, 3) void k_sweep(
    const __hip_bfloat16* __restrict__ lnbf,
    const _Float16* __restrict__ abrf,
    float2* __restrict__ rowslab,    // [16][B]
    float2* __restrict__ colslab,    // [64][B]
    float2* __restrict__ wsum, int B)
{
    __shared__ __hip_bfloat16 Bs[2][64 * 128];   // 32 KB double buffer
    __shared__ float2 colaccw[4 * 512];          // 16 KB per-wave col partials

    int bi = blockIdx.x, jc = blockIdx.y;
    int tid = threadIdx.x;
    int blk = jc * 64 + bi;
    int t0 = 2 * bi - 8 * jc;
    if (t0 < 0) t0 = 0;
    if (t0 >= TILES) {                           // fully below diagonal: zero wsum, exit
        if (tid < 4) wsum[(size_t)blk * 4 + tid] = make_float2(0.f, 0.f);
        return;
    }
    int i0 = bi * 128;

    int w = tid >> 6, l = tid & 63;
    int lr = l & 15, lg = l >> 4;

#pragma unroll
    for (int k = 0; k < 8; ++k) colaccw[k * 256 + tid] = make_float2(0.f, 0.f);

    // ---- A latent fragments: block-invariant, direct from global, 32 VGPR ----
    short8v a[4][2];
#pragma unroll
    for (int kk = 0; kk < 4; ++kk)
#pragma unroll
        for (int m = 0; m < 2; ++m)
            a[kk][m] = *reinterpret_cast<const short8v*>(
                lnbf + (size_t)(i0 + w * 32 + m * 16 + lr) * 128 + (kk * 4 + lg) * 8);

    // ---- abr A fragments: block-invariant ----
    half4v aa[2];
#pragma unroll
    for (int m = 0; m < 2; ++m)
        aa[m] = *reinterpret_cast<const half4v*>(
            abrf + (size_t)(i0 + w * 32 + m * 16 + lr) * 16 + lg * 4);

    // ---- stage helper: LDS(row, c) = global(row, c ^ (row & 15)); full-width involution ----
    auto stage = [&](int jt, int buf) {
        int j0 = jt * 64;
#pragma unroll
        for (int ro = 0; ro < 4; ++ro) {
            int rbase = w * 16 + ro * 4;
            int row = rbase + (l >> 4);
            int sch = (l & 15) ^ (row & 15);
            glds16(lnbf + (size_t)(j0 + row) * 128 + sch * 8, &Bs[buf][rbase * 128]);
        }
    };

    stage(jc * TILES + t0, 0);   // prologue

    float esum_r[2][4] = {{0.f}}, cnt_r[2][4] = {{0.f}};
    float sumd = 0.f, sumsim = 0.f;

#pragma unroll 1
    for (int t = t0; t < TILES; ++t) {
        int jt = jc * TILES + t;
        int cur = (t - t0) & 1;
        bool gated = ((jt >> 1) == bi);          // diag-straddling tile: keep col > row

        __syncthreads();   // stage(t) landed; all waves' reads of buf cur^1 are done

        if (t + 1 < TILES) stage(jt + 1, cur ^ 1);   // flight spans this tile's compute

        // abr B fragments direct from global
        half4v bb[4];
#pragma unroll
        for (int n = 0; n < 4; ++n)
            bb[n] = *reinterpret_cast<const half4v*>(
                abrf + (size_t)(jt * 64 + n * 16 + lr) * 16 + lg * 4);

        // ---- latent MFMA: b frags from LDS (swizzled read), a from regs ----
        f32x4 acc[2][4];
#pragma unroll
        for (int m = 0; m < 2; ++m)
#pragma unroll
            for (int n = 0; n < 4; ++n) acc[m][n] = (f32x4){0.f, 0.f, 0.f, 0.f};
#pragma unroll
        for (int kk = 0; kk < 4; ++kk) {
            short8v b[4];
#pragma unroll
            for (int n = 0; n < 4; ++n) {
                int jl = n * 16 + lr;
                int ch = (kk * 4 + lg) ^ lr;
                b[n] = *reinterpret_cast<const short8v*>(&Bs[cur][jl * 128 + ch * 8]);
            }
#pragma unroll
            for (int m = 0; m < 2; ++m)
#pragma unroll
                for (int n = 0; n < 4; ++n)
                    acc[m][n] = __builtin_amdgcn_mfma_f32_16x16x32_bf16(a[kk][m], b[n], acc[m][n], 0, 0, 0);
        }

        // ---- merged epilogue (m-outer, R14 shape) + col-mirror register partials ----
        float ce[4] = {0.f, 0.f, 0.f, 0.f}, cp[4] = {0.f, 0.f, 0.f, 0.f};
#pragma unroll
        for (int m = 0; m < 2; ++m) {
#pragma unroll
            for (int n = 0; n < 4; ++n) {
                f32x4 aacc = __builtin_amdgcn_mfma_f32_16x16x16f16(
                    aa[m], bb[n], (f32x4){0.f, 0.f, 0.f, 0.f}, 0, 0, 0);
#pragma unroll
                for (int r = 0; r < 4; ++r) {
                    float d = acc[m][n][r];       // = s_ij * log2(e)
                    float sim = aacc[r];
                    float e = fexp2(d);
                    bool pred = sim > SIM_THR;
                    if (gated) {
                        bool keep = (jt * 64 + n * 16 + lr) > (i0 + w * 32 + m * 16 + lg * 4 + r);
                        if (!keep) { e = 0.f; pred = false; }
                    }
                    float p = pred ? 1.f : 0.f;
                    esum_r[m][r] += e;
                    cnt_r[m][r] += p;
                    sumsim = fmaf(p, sim, sumsim);
                    sumd = fmaf(p, d, sumd);
                    ce[n] += e;
                    cp[n] += p;
                }
            }
        }
        // col partials: reduce over the 4 row-groups (lg), store to this wave's slot
#pragma unroll
        for (int n = 0; n < 4; ++n) {
            float e2 = ce[n], p2 = cp[n];
            e2 += __shfl_xor(e2, 16); e2 += __shfl_xor(e2, 32);
            p2 += __shfl_xor(p2, 16); p2 += __shfl_xor(p2, 32);
            if (lg == 0)
                colaccw[w * 512 + t * 64 + n * 16 + lr] = make_float2(e2, p2);
        }
    }

    // ---- per-row: reduce over 16 col-lanes, write rowslab ----
#pragma unroll
    for (int m = 0; m < 2; ++m)
#pragma unroll
        for (int r = 0; r < 4; ++r) {
            float a0 = esum_r[m][r], a1 = cnt_r[m][r];
#pragma unroll
            for (int d2 = 1; d2 < 16; d2 <<= 1) {
                a0 += __shfl_xor(a0, d2);
                a1 += __shfl_xor(a1, d2);
            }
            if (lr == 0) {
                int row_g = i0 + w * 32 + m * 16 + lg * 4 + r;
                rowslab[(size_t)jc * B + row_g] = make_float2(a0, a1);
            }
        }

    // ---- per-wave scalar partials ----
#pragma unroll
    for (int d2 = 1; d2 < 64; d2 <<= 1) {
        sumd += __shfl_xor(sumd, d2);
        sumsim += __shfl_xor(sumsim, d2);
    }
    if (l == 0) wsum[(size_t)blk * 4 + w] = make_float2(sumd, sumsim);

    // ---- combine 4 waves' col partials, write colslab ----
    __syncthreads();
#pragma unroll
    for (int k = 0; k < 2; ++k) {
        int cidx = k * 256 + tid;
        float2 v0 = colaccw[cidx], v1 = colaccw[512 + cidx];
        float2 v2 = colaccw[1024 + cidx], v3 = colaccw[1536 + cidx];
        colslab[(size_t)bi * B + jc * 512 + cidx] =
            make_float2(v0.x + v1.x + v2.x + v3.x, v0.y + v1.y + v2.y + v3.y);
    }
}

// ---------------- per-row finalize + block partials ----------------
__global__ __launch_bounds__(256) void k_rows(const float2* __restrict__ rowslab,
                                              const float2* __restrict__ colslab,
                                              float* __restrict__ pC,
                                              float* __restrict__ pLN, int B) {
    __shared__ float sc[4], sl[4];
    int tid = threadIdx.x;
    int i = blockIdx.x * 256 + tid;
    int bi = i >> 7;
    float S = 0.f, c = 0.f;
    for (int jc = bi >> 2; jc < 16; ++jc) {      // active blocks only (bi <= 4*jc+3)
        float2 v = rowslab[(size_t)jc * B + i];
        S += v.x; c += v.y;
    }
    for (int b2 = 0; b2 <= bi; ++b2) {           // inclusive: in-panel mirrors live in colslab[bi]
        float2 v = colslab[(size_t)b2 * B + i];
        S += v.x; c += v.y;
    }
    float ln = (c > 0.f) ? c * logf(S) : 0.f;
#pragma unroll
    for (int d = 1; d < 64; d <<= 1) {
        c += __shfl_xor(c, d); ln += __shfl_xor(ln, d);
    }
    int wave = tid >> 6, lane = tid & 63;
    if (lane == 0) { sc[wave] = c; sl[wave] = ln; }
    __syncthreads();
    if (tid == 0) {
        pC[blockIdx.x] = sc[0] + sc[1] + sc[2] + sc[3];
        pLN[blockIdx.x] = sl[0] + sl[1] + sl[2] + sl[3];
    }
}

// ---------------- final: combine row partials + wave scalar partials ----------------
__global__ __launch_bounds__(256) void k_final(const float* __restrict__ pC,
                                               const float* __restrict__ pLN,
                                               const float2* __restrict__ wsum,
                                               float* __restrict__ out,
                                               int nrb, int nw, float npairs) {
    __shared__ float s0[4], s1[4], s2[4], s3[4];
    int tid = threadIdx.x;
    float c = 0.f, ln = 0.f, sd = 0.f, sm = 0.f;
    for (int e = tid; e < nw; e += 256) {
        float2 v = wsum[e];
        sd += v.x; sm += v.y;
    }
    if (tid < nrb) { c = pC[tid]; ln = pLN[tid]; }
#pragma unroll
    for (int d = 1; d < 64; d <<= 1) {
        c += __shfl_xor(c, d); ln += __shfl_xor(ln, d);
        sd += __shfl_xor(sd, d); sm += __shfl_xor(sm, d);
    }
    int wave = tid >> 6, lane = tid & 63;
    if (lane == 0) { s0[wave] = c; s1[wave] = ln; s2[wave] = sd; s3[wave] = sm; }
    __syncthreads();
    if (tid == 0) {
        float ct = s0[0] + s0[1] + s0[2] + s0[3];
        float lt = s1[0] + s1[1] + s1[2] + s1[3];
        float st = 2.f * (s2[0] + s2[1] + s2[2] + s2[3]);   // unordered -> ordered
        float mt = 2.f * (s3[0] + s3[1] + s3[2] + s3[3]);
        out[0] = (ct > 0.f) ? (lt - LN2 * st) / ct : 0.f;
        out[1] = (ct > 0.f) ? mt / ct : 0.f;
        out[2] = ct;
        out[3] = ct / npairs;
    }
}

extern "C" void kernel_launch(void* const* d_in, const int* in_sizes, int n_in,
                              void* d_out, int out_size, void* d_ws, size_t ws_size,
                              hipStream_t stream) {
    const float* lat = (const float*)d_in[0];
    const float* abr = (const float*)d_in[1];
    float* out = (float*)d_out;
    int B = in_sizes[1] / 6;  // 8192

    char* ws = (char*)d_ws;
    size_t off = 0;
    __hip_bfloat16* lnbf = (__hip_bfloat16*)(ws + off); off += (size_t)B * 128 * 2;  // 2 MB
    _Float16* abrf = (_Float16*)(ws + off); off += (size_t)B * 16 * 2;               // 256 KB
    float2* rowslab = (float2*)(ws + off); off += (size_t)16 * B * 8;                // 1 MB
    float2* colslab = (float2*)(ws + off); off += (size_t)64 * B * 8;                // 4 MB
    int nblk = 16 * 64;   // 1024 grid slots (inactive write zeros)
    float2* wsum = (float2*)(ws + off); off += (size_t)nblk * 4 * 8;                 // 32 KB
    int nrb = B / 256;  // 32
    float* pC = (float*)(ws + off); off += (size_t)nrb * 4;
    float* pLN = (float*)(ws + off); off += (size_t)nrb * 4;

    k_norm<<<B / 4 + B / 256, 256, 0, stream>>>(lat, abr, lnbf, abrf, B);
    k_sweep<<<dim3(64, 16), 256, 0, stream>>>(lnbf, abrf, rowslab, colslab, wsum, B);
    k_rows<<<nrb, 256, 0, stream>>>(rowslab, colslab, pC, pLN, B);
    k_final<<<1, 256, 0, stream>>>(pC, pLN, wsum, out, nrb, nblk * 4, (float)B * (float)(B - 1));
}

// Round 18
// 52.930 us; speedup vs baseline: 1.9643x; 1.9643x over previous
//
#include <hip/hip_runtime.h>
#include <hip/hip_bf16.h>
#include <math.h>

#define SIM_THR 0.8f
// sqrt(2 * log2(e)): folds the /T=0.5 and the exp->exp2 conversion into the data
#define LAT_SCALE 1.6986436f
#define LN2 0.6931471805599453f
#define TILES 8   // j-tiles of 64 cols per block

typedef __attribute__((ext_vector_type(8))) short short8v;   // 8 bf16
typedef __attribute__((ext_vector_type(4))) float f32x4;
typedef __attribute__((ext_vector_type(4))) _Float16 half4v; // 4 f16

__device__ __forceinline__ void glds16(const void* g, void* l) {
    __builtin_amdgcn_global_load_lds(
        (const __attribute__((address_space(1))) void*)g,
        (__attribute__((address_space(3))) void*)l, 16, 0, 0);
}

__device__ __forceinline__ float fexp2(float x) {
#if __has_builtin(__builtin_amdgcn_exp2f)
    return __builtin_amdgcn_exp2f(x);
#else
    return exp2f(x);
#endif
}

// ---------------- fused normalize: lat rows -> bf16 (scaled) + abr rows -> f16 ----------------
__global__ __launch_bounds__(256) void k_norm(const float* __restrict__ lat,
                                              const float* __restrict__ abr,
                                              __hip_bfloat16* __restrict__ lout,
                                              _Float16* __restrict__ aout, int B) {
    int nb_lat = B / 4;  // 2048
    if ((int)blockIdx.x < nb_lat) {
        int row = blockIdx.x * 4 + (threadIdx.x >> 6);
        int lane = threadIdx.x & 63;
        float2 v = reinterpret_cast<const float2*>(lat + (size_t)row * 128)[lane];
        float ss = v.x * v.x + v.y * v.y;
#pragma unroll
        for (int m = 1; m < 64; m <<= 1) ss += __shfl_xor(ss, m);
        float sc = LAT_SCALE / fmaxf(sqrtf(ss), 1e-12f);
        __hip_bfloat162 o;
        o.x = __float2bfloat16(v.x * sc);
        o.y = __float2bfloat16(v.y * sc);
        reinterpret_cast<__hip_bfloat162*>(lout + (size_t)row * 128)[lane] = o;
    } else {
        int row = (blockIdx.x - nb_lat) * 256 + threadIdx.x;
        if (row >= B) return;
        float v[6];
        float ss = 0.f;
#pragma unroll
        for (int d = 0; d < 6; ++d) { v[d] = abr[(size_t)row * 6 + d]; ss += v[d] * v[d]; }
        float sc = 1.0f / fmaxf(sqrtf(ss), 1e-12f);
#pragma unroll
        for (int d = 0; d < 6; ++d) aout[(size_t)row * 16 + d] = (_Float16)(v[d] * sc);
#pragma unroll
        for (int d = 6; d < 16; ++d) aout[(size_t)row * 16 + d] = (_Float16)0.f;
    }
}

// ---------------- fused sweep (champion config: R12) ----------------
// Block (jc, bi): 128 rows x 64-col j-tiles, 8 tiles. Wave tile 32x64 (acc[2][4]).
// A latent fragments hoisted to registers (32 VGPR) straight from global (once per block).
// Per tile: barrier -> stage(t+1 -> buf^1) -> MFMA(buf) -> epilogue. One barrier/tile;
// stage flight spans the whole tile's compute.
__global__ __launch_bounds__(256, 3) void k_sweep(
    const __hip_bfloat16* __restrict__ lnbf,
    const _Float16* __restrict__ abrf,
    float2* __restrict__ slab, float2* __restrict__ wsum, int B)
{
    __shared__ __hip_bfloat16 Bs[2][64 * 128];   // 32 KB double buffer

    int jc = blockIdx.x, bi = blockIdx.y;
    int i0 = bi * 128;
    int tid = threadIdx.x;
    int w = tid >> 6, l = tid & 63;
    int lr = l & 15, lg = l >> 4;

    // ---- A latent fragments: block-invariant, direct from global, 32 VGPR ----
    short8v a[4][2];
#pragma unroll
    for (int kk = 0; kk < 4; ++kk)
#pragma unroll
        for (int m = 0; m < 2; ++m)
            a[kk][m] = *reinterpret_cast<const short8v*>(
                lnbf + (size_t)(i0 + w * 32 + m * 16 + lr) * 128 + (kk * 4 + lg) * 8);

    // ---- abr A fragments: block-invariant ----
    half4v aa[2];
#pragma unroll
    for (int m = 0; m < 2; ++m)
        aa[m] = *reinterpret_cast<const half4v*>(
            abrf + (size_t)(i0 + w * 32 + m * 16 + lr) * 16 + lg * 4);

    // ---- stage helper: 64-row j-tile, linear LDS dest, XOR-pre-swizzled source ----
    auto stage = [&](int jt, int buf) {
        int j0 = jt * 64;
#pragma unroll
        for (int ro = 0; ro < 4; ++ro) {
            int rbase = w * 16 + ro * 4;
            int row = rbase + (l >> 4);
            int sch = (l & 15) ^ (row & 7);
            glds16(lnbf + (size_t)(j0 + row) * 128 + sch * 8, &Bs[buf][rbase * 128]);
        }
    };

    stage(jc * TILES, 0);   // prologue

    float esum_r[2][4] = {{0.f}}, cnt_r[2][4] = {{0.f}};
    float sumd = 0.f, sumsim = 0.f;

#pragma unroll 1
    for (int t = 0; t < TILES; ++t) {
        int jt = jc * TILES + t;
        int cur = t & 1;
        bool dtile = ((jt >> 1) == bi);
        int joff = (jt & 1) * 64;

        __syncthreads();   // stage(t) landed (per-wave vmcnt drained before barrier);
                           // also: all waves' reads of buf cur^1 (iter t-1) are done

        if (t + 1 < TILES) stage(jt + 1, cur ^ 1);   // flight spans this tile's compute

        // abr B fragments direct from global
        half4v bb[4];
#pragma unroll
        for (int n = 0; n < 4; ++n)
            bb[n] = *reinterpret_cast<const half4v*>(
                abrf + (size_t)(jt * 64 + n * 16 + lr) * 16 + lg * 4);

        // ---- latent MFMA: b frags from LDS (swizzled), a from regs ----
        f32x4 acc[2][4];
#pragma unroll
        for (int m = 0; m < 2; ++m)
#pragma unroll
            for (int n = 0; n < 4; ++n) acc[m][n] = (f32x4){0.f, 0.f, 0.f, 0.f};
#pragma unroll
        for (int kk = 0; kk < 4; ++kk) {
            short8v b[4];
#pragma unroll
            for (int n = 0; n < 4; ++n) {
                int jl = n * 16 + lr;
                int ch = (kk * 4 + lg) ^ (jl & 7);
                b[n] = *reinterpret_cast<const short8v*>(&Bs[cur][jl * 128 + ch * 8]);
            }
#pragma unroll
            for (int m = 0; m < 2; ++m)
#pragma unroll
                for (int n = 0; n < 4; ++n)
                    acc[m][n] = __builtin_amdgcn_mfma_f32_16x16x32_bf16(a[kk][m], b[n], acc[m][n], 0, 0, 0);
        }

        // ---- merged epilogue: abr MFMA + fused stats (registers only) ----
#pragma unroll
        for (int m = 0; m < 2; ++m) {
#pragma unroll
            for (int n = 0; n < 4; ++n) {
                f32x4 aacc = __builtin_amdgcn_mfma_f32_16x16x16f16(
                    aa[m], bb[n], (f32x4){0.f, 0.f, 0.f, 0.f}, 0, 0, 0);
#pragma unroll
                for (int r = 0; r < 4; ++r) {
                    float d = acc[m][n][r];       // = s_ij * log2(e)
                    float sim = aacc[r];
                    float e = fexp2(d);
                    bool pred = sim > SIM_THR;
                    if (dtile) {
                        bool dg = (w * 32 + m * 16 + lg * 4 + r) == (joff + n * 16 + lr);
                        if (dg) { e = 0.f; pred = false; }
                    }
                    float p = pred ? 1.f : 0.f;
                    esum_r[m][r] += e;
                    cnt_r[m][r] += p;
                    sumsim = fmaf(p, sim, sumsim);
                    sumd = fmaf(p, d, sumd);
                }
            }
        }
    }

    // ---- per-row: reduce over 16 col-lanes, one float2 per row (unique owner) ----
#pragma unroll
    for (int m = 0; m < 2; ++m)
#pragma unroll
        for (int r = 0; r < 4; ++r) {
            float a0 = esum_r[m][r], a1 = cnt_r[m][r];
#pragma unroll
            for (int d2 = 1; d2 < 16; d2 <<= 1) {
                a0 += __shfl_xor(a0, d2);
                a1 += __shfl_xor(a1, d2);
            }
            if (lr == 0) {
                int row_g = i0 + w * 32 + m * 16 + lg * 4 + r;
                slab[(size_t)jc * B + row_g] = make_float2(a0, a1);
            }
        }

    // ---- per-wave scalar partials ----
#pragma unroll
    for (int d2 = 1; d2 < 64; d2 <<= 1) {
        sumd += __shfl_xor(sumd, d2);
        sumsim += __shfl_xor(sumsim, d2);
    }
    if (l == 0)
        wsum[(size_t)(bi * 16 + jc) * 4 + w] = make_float2(sumd, sumsim);
}

// ---------------- per-row finalize + block partials ----------------
__global__ __launch_bounds__(256) void k_rows(const float2* __restrict__ slab,
                                              float* __restrict__ pC,
                                              float* __restrict__ pLN, int B) {
    __shared__ float sc[4], sl[4];
    int tid = threadIdx.x;
    int i = blockIdx.x * 256 + tid;
    float S = 0.f, c = 0.f;
#pragma unroll
    for (int k = 0; k < 16; ++k) {
        float2 v = slab[(size_t)k * B + i];
        S += v.x; c += v.y;
    }
    float ln = c * logf(S);   // c==0 -> 0; S > 0 always
#pragma unroll
    for (int d = 1; d < 64; d <<= 1) {
        c += __shfl_xor(c, d); ln += __shfl_xor(ln, d);
    }
    int wave = tid >> 6, lane = tid & 63;
    if (lane == 0) { sc[wave] = c; sl[wave] = ln; }
    __syncthreads();
    if (tid == 0) {
        pC[blockIdx.x] = sc[0] + sc[1] + sc[2] + sc[3];
        pLN[blockIdx.x] = sl[0] + sl[1] + sl[2] + sl[3];
    }
}

// ---------------- final: combine row partials + wave scalar partials ----------------
__global__ __launch_bounds__(256) void k_final(const float* __restrict__ pC,
                                               const float* __restrict__ pLN,
                                               const float2* __restrict__ wsum,
                                               float* __restrict__ out,
                                               int nrb, int nw, float npairs) {
    __shared__ float s0[4], s1[4], s2[4], s3[4];
    int tid = threadIdx.x;
    float c = 0.f, ln = 0.f, sd = 0.f, sm = 0.f;
    for (int e = tid; e < nw; e += 256) {
        float2 v = wsum[e];
        sd += v.x; sm += v.y;
    }
    if (tid < nrb) { c = pC[tid]; ln = pLN[tid]; }
#pragma unroll
    for (int d = 1; d < 64; d <<= 1) {
        c += __shfl_xor(c, d); ln += __shfl_xor(ln, d);
        sd += __shfl_xor(sd, d); sm += __shfl_xor(sm, d);
    }
    int wave = tid >> 6, lane = tid & 63;
    if (lane == 0) { s0[wave] = c; s1[wave] = ln; s2[wave] = sd; s3[wave] = sm; }
    __syncthreads();
    if (tid == 0) {
        float ct = s0[0] + s0[1] + s0[2] + s0[3];
        float lt = s1[0] + s1[1] + s1[2] + s1[3];
        float st = s2[0] + s2[1] + s2[2] + s2[3];
        float mt = s3[0] + s3[1] + s3[2] + s3[3];
        out[0] = (ct > 0.f) ? (lt - LN2 * st) / ct : 0.f;
        out[1] = (ct > 0.f) ? mt / ct : 0.f;
        out[2] = ct;
        out[3] = ct / npairs;
    }
}

extern "C" void kernel_launch(void* const* d_in, const int* in_sizes, int n_in,
                              void* d_out, int out_size, void* d_ws, size_t ws_size,
                              hipStream_t stream) {
    const float* lat = (const float*)d_in[0];
    const float* abr = (const float*)d_in[1];
    float* out = (float*)d_out;
    int B = in_sizes[1] / 6;  // 8192

    char* ws = (char*)d_ws;
    size_t off = 0;
    __hip_bfloat16* lnbf = (__hip_bfloat16*)(ws + off); off += (size_t)B * 128 * 2;  // 2 MB
    _Float16* abrf = (_Float16*)(ws + off); off += (size_t)B * 16 * 2;               // 256 KB
    float2* slab = (float2*)(ws + off); off += (size_t)16 * B * 8;                   // 1 MB
    int nblk = 16 * (B / 128);          // 1024
    float2* wsum = (float2*)(ws + off); off += (size_t)nblk * 4 * 8;                 // 32 KB
    int nrb = B / 256;  // 32
    float* pC = (float*)(ws + off); off += (size_t)nrb * 4;
    float* pLN = (float*)(ws + off); off += (size_t)nrb * 4;

    k_norm<<<B / 4 + B / 256, 256, 0, stream>>>(lat, abr, lnbf, abrf, B);
    k_sweep<<<dim3(16, B / 128), 256, 0, stream>>>(lnbf, abrf, slab, wsum, B);
    k_rows<<<nrb, 256, 0, stream>>>(slab, pC, pLN, B);
    k_final<<<1, 256, 0, stream>>>(pC, pLN, wsum, out, nrb, nblk * 4, (float)B * (float)(B - 1));
}